// Round 6
// baseline (408.957 us; speedup 1.0000x reference)
//
#include <hip/hip_runtime.h>
#include <math.h>

#define NN 102400
#define D 256
#define B 2048

typedef __bf16 bf16x8 __attribute__((ext_vector_type(8)));
typedef float f32x4 __attribute__((ext_vector_type(4)));

// K0: seg_start[b] = lower_bound(seg_ids, b); seg_start[B] = NN
__global__ void k_bounds(const int* __restrict__ seg, int* __restrict__ seg_start) {
    int b = blockIdx.x * blockDim.x + threadIdx.x;
    if (b > B) return;
    int lo = 0, hi = NN;
    while (lo < hi) { int mid = (lo + hi) >> 1; if (seg[mid] < b) lo = mid + 1; else hi = mid; }
    seg_start[b] = lo;
}

// K1: anchor (segment mean) -> out[:, 256:512]
__global__ void k_anchor(const float* __restrict__ ifeat, const int* __restrict__ seg_start,
                         float* __restrict__ out) {
    int b = blockIdx.x;
    int t = threadIdx.x; // 256 threads, thread = column
    int s = seg_start[b], e = seg_start[b + 1];
    float a0 = 0.f, a1 = 0.f, a2 = 0.f, a3 = 0.f;
    int i = s;
    for (; i + 4 <= e; i += 4) {
        a0 += ifeat[(size_t)(i + 0) * D + t];
        a1 += ifeat[(size_t)(i + 1) * D + t];
        a2 += ifeat[(size_t)(i + 2) * D + t];
        a3 += ifeat[(size_t)(i + 3) * D + t];
    }
    for (; i < e; ++i) a0 += ifeat[(size_t)i * D + t];
    float sum = (a0 + a1) + (a2 + a3);
    int cnt = e - s;
    float inv = 1.0f / (float)(cnt > 0 ? cnt : 1);
    out[(size_t)b * 512 + 256 + t] = sum * inv;
}

// K2: feat_v = anchor @ Wv^T + bv, 16 segments per block
__global__ void k_featv(const float* __restrict__ out, const float* __restrict__ Wv,
                        const float* __restrict__ bv, float* __restrict__ feat_v) {
    __shared__ float anc[16][D];
    int b0 = blockIdx.x * 16;
    int t = threadIdx.x; // 256, thread = output column j
#pragma unroll
    for (int r = 0; r < 16; ++r) anc[r][t] = out[(size_t)(b0 + r) * 512 + 256 + t];
    __syncthreads();
    float acc[16];
#pragma unroll
    for (int s = 0; s < 16; ++s) acc[s] = 0.f;
    const float* wrow = Wv + (size_t)t * D;
    for (int k = 0; k < D; k += 4) {
        float4 w = *(const float4*)(wrow + k);
#pragma unroll
        for (int s = 0; s < 16; ++s) {
            acc[s] += anc[s][k] * w.x + anc[s][k + 1] * w.y
                    + anc[s][k + 2] * w.z + anc[s][k + 3] * w.w;
        }
    }
    float bj = bv[t];
#pragma unroll
    for (int s = 0; s < 16; ++s) feat_v[(size_t)(b0 + s) * D + t] = acc[s] + bj;
}

// K3 (MFMA, Wu-resident, low-VGPR): e[n] = we . sigmoid(bf16(ifeat[n]) @ bf16(Wu)^T + fv)
// 256 blocks x 512 thr. Wu staged ONCE into 128 KB LDS (bf16, XOR-swizzled).
// Rounds 3-5 lesson: compiler pins 128 VGPRs; acc[16] (64 regs) + extras spilled
// (207 MB scratch WRITE). Fix: col-group-OUTER loop — A held as 8 named bf16x8
// frags (32 regs), only 4 f32x4 accumulators live at a time (~90 regs peak).
__global__ __launch_bounds__(512, 1)
void k_attn_e_mfma(const float* __restrict__ ifeat, const float* __restrict__ Wu,
                   const float* __restrict__ feat_v, const float* __restrict__ we,
                   const int* __restrict__ seg_ids, float* __restrict__ e_out) {
    __shared__ __bf16 Bs[256 * 256];   // [j][k] bf16, byte addr = j*512 + (k*2 ^ ((j&7)<<4))

    int tx = threadIdx.x;
    int lane = tx & 63;
    int w = tx >> 6;
    int ln15 = lane & 15;
    int lg = lane >> 4;

    // ---- stage Wu once: thread -> (row j = tx>>1, k-half h = tx&1), 128 elems each ----
    {
        int j = tx >> 1, h = tx & 1;
        const float* wp = Wu + (size_t)j * D + h * 128;
        char* rowp = (char*)Bs + j * 512;
        int sw = (j & 7) << 4;
#pragma unroll
        for (int q = 0; q < 16; ++q) {
            float4 b0 = *(const float4*)(wp + q * 8);
            float4 b1 = *(const float4*)(wp + q * 8 + 4);
            bf16x8 v;
            v[0] = (__bf16)b0.x; v[1] = (__bf16)b0.y; v[2] = (__bf16)b0.z; v[3] = (__bf16)b0.w;
            v[4] = (__bf16)b1.x; v[5] = (__bf16)b1.y; v[6] = (__bf16)b1.z; v[7] = (__bf16)b1.w;
            *(bf16x8*)(rowp + ((h * 256 + q * 16) ^ sw)) = v;
        }
    }
    __syncthreads();

    int wave_gid = blockIdx.x * 8 + w;
    int swr = (ln15 & 7) << 4;            // read-side swizzle (row&7 == ln15&7)
    int klo = lg * 16;
    const char* bbase = (const char*)Bs + ln15 * 512;

    for (int item = wave_gid; item < NN / 16; item += 2048) {
        int nb = item * 16;
        const float* ap = ifeat + (size_t)(nb + ln15) * D + lg * 8;

        // ---- load + cvt full A row-block: 8 named bf16x8 frags (32 VGPRs) ----
        bf16x8 af0, af1, af2, af3, af4, af5, af6, af7;
        {
            float4 x0, y0, x1, y1;   // 2-deep named pipeline, all-static
#define LDA0(CH) { x0 = *(const float4*)(ap + (CH) * 32); y0 = *(const float4*)(ap + (CH) * 32 + 4); }
#define LDA1(CH) { x1 = *(const float4*)(ap + (CH) * 32); y1 = *(const float4*)(ap + (CH) * 32 + 4); }
#define CVTA(AF, X, Y) { \
    AF[0] = (__bf16)X.x; AF[1] = (__bf16)X.y; AF[2] = (__bf16)X.z; AF[3] = (__bf16)X.w; \
    AF[4] = (__bf16)Y.x; AF[5] = (__bf16)Y.y; AF[6] = (__bf16)Y.z; AF[7] = (__bf16)Y.w; }
            LDA0(0); LDA1(1); CVTA(af0, x0, y0);
            LDA0(2);          CVTA(af1, x1, y1);
            LDA1(3);          CVTA(af2, x0, y0);
            LDA0(4);          CVTA(af3, x1, y1);
            LDA1(5);          CVTA(af4, x0, y0);
            LDA0(6);          CVTA(af5, x1, y1);
            LDA1(7);          CVTA(af6, x0, y0);
                              CVTA(af7, x1, y1);
#undef LDA0
#undef LDA1
#undef CVTA
        }

        // ---- epilogue state: per-row feat_v pointers + running e partials ----
        int r0 = nb + lg * 4;
        const float* fp0 = feat_v + (size_t)seg_ids[r0 + 0] * D + ln15;
        const float* fp1 = feat_v + (size_t)seg_ids[r0 + 1] * D + ln15;
        const float* fp2 = feat_v + (size_t)seg_ids[r0 + 2] * D + ln15;
        const float* fp3 = feat_v + (size_t)seg_ids[r0 + 3] * D + ln15;
        float part0 = 0.f, part1 = 0.f, part2 = 0.f, part3 = 0.f;

        // per col-tile ct (16 cols), rows at ct*16*512 B; per chunk CH: k window
#define MSTEP(AF, CH, CT0) { \
    int kb = ((CH) * 64 + klo) ^ swr; \
    bf16x8 b0 = *(const bf16x8*)(bbase + ((CT0) + 0) * 8192 + kb); \
    bf16x8 b1 = *(const bf16x8*)(bbase + ((CT0) + 1) * 8192 + kb); \
    bf16x8 b2 = *(const bf16x8*)(bbase + ((CT0) + 2) * 8192 + kb); \
    bf16x8 b3 = *(const bf16x8*)(bbase + ((CT0) + 3) * 8192 + kb); \
    a0 = __builtin_amdgcn_mfma_f32_16x16x32_bf16(AF, b0, a0, 0, 0, 0); \
    a1 = __builtin_amdgcn_mfma_f32_16x16x32_bf16(AF, b1, a1, 0, 0, 0); \
    a2 = __builtin_amdgcn_mfma_f32_16x16x32_bf16(AF, b2, a2, 0, 0, 0); \
    a3 = __builtin_amdgcn_mfma_f32_16x16x32_bf16(AF, b3, a3, 0, 0, 0); }

#define EPI1(AC, CT) { \
    float w_ = we[(CT) * 16 + ln15]; \
    { float u = AC[0] + fp0[(CT) * 16]; part0 += w_ / (1.f + __expf(-u)); } \
    { float u = AC[1] + fp1[(CT) * 16]; part1 += w_ / (1.f + __expf(-u)); } \
    { float u = AC[2] + fp2[(CT) * 16]; part2 += w_ / (1.f + __expf(-u)); } \
    { float u = AC[3] + fp3[(CT) * 16]; part3 += w_ / (1.f + __expf(-u)); } }

#define CTG_BLOCK(CTG_) { \
    f32x4 a0 = (f32x4){0.f, 0.f, 0.f, 0.f}; \
    f32x4 a1 = (f32x4){0.f, 0.f, 0.f, 0.f}; \
    f32x4 a2 = (f32x4){0.f, 0.f, 0.f, 0.f}; \
    f32x4 a3 = (f32x4){0.f, 0.f, 0.f, 0.f}; \
    MSTEP(af0, 0, (CTG_) * 4) \
    MSTEP(af1, 1, (CTG_) * 4) \
    MSTEP(af2, 2, (CTG_) * 4) \
    MSTEP(af3, 3, (CTG_) * 4) \
    MSTEP(af4, 4, (CTG_) * 4) \
    MSTEP(af5, 5, (CTG_) * 4) \
    MSTEP(af6, 6, (CTG_) * 4) \
    MSTEP(af7, 7, (CTG_) * 4) \
    EPI1(a0, (CTG_) * 4 + 0) \
    EPI1(a1, (CTG_) * 4 + 1) \
    EPI1(a2, (CTG_) * 4 + 2) \
    EPI1(a3, (CTG_) * 4 + 3) }

        CTG_BLOCK(0)
        CTG_BLOCK(1)
        CTG_BLOCK(2)
        CTG_BLOCK(3)
#undef MSTEP
#undef EPI1
#undef CTG_BLOCK

        // ---- reduce e over the 16 col-lanes ----
#pragma unroll
        for (int off = 8; off >= 1; off >>= 1) {
            part0 += __shfl_xor(part0, off, 64);
            part1 += __shfl_xor(part1, off, 64);
            part2 += __shfl_xor(part2, off, 64);
            part3 += __shfl_xor(part3, off, 64);
        }
        if (ln15 == 0) {
            float4 o = make_float4(part0, part1, part2, part3);
            *(float4*)&e_out[r0] = o;
        }
    }
}

// K4: segment softmax (max, denom) + alpha-weighted segment sum -> out[:, 0:256]
__global__ void k_softmax_rst(const float* __restrict__ ifeat, const int* __restrict__ seg_start,
                              const float* __restrict__ e, float* __restrict__ out) {
    int b = blockIdx.x;
    int t = threadIdx.x; // 256
    int s = seg_start[b], en = seg_start[b + 1];
    float m = -1e30f;
    for (int i = s + t; i < en; i += 256) m = fmaxf(m, e[i]);
#pragma unroll
    for (int off = 32; off >= 1; off >>= 1) m = fmaxf(m, __shfl_xor(m, off, 64));
    __shared__ float red[4];
    if ((t & 63) == 0) red[t >> 6] = m;
    __syncthreads();
    float mall = fmaxf(fmaxf(red[0], red[1]), fmaxf(red[2], red[3]));
    float dsum = 0.f;
    for (int i = s + t; i < en; i += 256) dsum += __expf(e[i] - mall);
#pragma unroll
    for (int off = 32; off >= 1; off >>= 1) dsum += __shfl_xor(dsum, off, 64);
    __shared__ float red2[4];
    if ((t & 63) == 0) red2[t >> 6] = dsum;
    __syncthreads();
    float denom = red2[0] + red2[1] + red2[2] + red2[3];
    float invd = (en > s) ? 1.0f / denom : 0.f;
    float acc = 0.f;
    for (int i = s; i < en; ++i) {
        float alpha = __expf(e[i] - mall) * invd;
        acc += ifeat[(size_t)i * D + t] * alpha;
    }
    out[(size_t)b * 512 + t] = acc;
}

extern "C" void kernel_launch(void* const* d_in, const int* in_sizes, int n_in,
                              void* d_out, int out_size, void* d_ws, size_t ws_size,
                              hipStream_t stream) {
    const float* ifeat = (const float*)d_in[0];
    const float* Wu    = (const float*)d_in[1];
    const float* Wv    = (const float*)d_in[2];
    const float* bv    = (const float*)d_in[3];
    const float* we    = (const float*)d_in[4];
    const int*   seg   = (const int*)d_in[5];
    float* out = (float*)d_out;

    char* ws = (char*)d_ws;
    int*   seg_start = (int*)ws;                                   // (B+1) ints
    float* feat_v    = (float*)(ws + 16384);                       // B*D floats (2 MB)
    float* e_buf     = (float*)(ws + 16384 + (size_t)B * D * 4);   // NN floats (400 KB)

    k_bounds<<<(B + 1 + 255) / 256, 256, 0, stream>>>(seg, seg_start);
    k_anchor<<<B, 256, 0, stream>>>(ifeat, seg_start, out);
    k_featv<<<B / 16, 256, 0, stream>>>(out, Wv, bv, feat_v);
    k_attn_e_mfma<<<256, 512, 0, stream>>>(ifeat, Wu, feat_v, we, seg, e_buf);
    k_softmax_rst<<<B, 256, 0, stream>>>(ifeat, seg_start, e_buf, out);
}

// Round 7
// 200.203 us; speedup vs baseline: 2.0427x; 2.0427x over previous
//
#include <hip/hip_runtime.h>
#include <math.h>

#define NN 102400
#define D 256
#define B 2048

typedef __bf16 bf16x8 __attribute__((ext_vector_type(8)));
typedef float f32x4 __attribute__((ext_vector_type(4)));

// K0: seg_start[b] = lower_bound(seg_ids, b); seg_start[B] = NN
__global__ void k_bounds(const int* __restrict__ seg, int* __restrict__ seg_start) {
    int b = blockIdx.x * blockDim.x + threadIdx.x;
    if (b > B) return;
    int lo = 0, hi = NN;
    while (lo < hi) { int mid = (lo + hi) >> 1; if (seg[mid] < b) lo = mid + 1; else hi = mid; }
    seg_start[b] = lo;
}

// K1: anchor (segment mean) -> out[:, 256:512]
__global__ void k_anchor(const float* __restrict__ ifeat, const int* __restrict__ seg_start,
                         float* __restrict__ out) {
    int b = blockIdx.x;
    int t = threadIdx.x; // 256 threads, thread = column
    int s = seg_start[b], e = seg_start[b + 1];
    float a0 = 0.f, a1 = 0.f, a2 = 0.f, a3 = 0.f;
    int i = s;
    for (; i + 4 <= e; i += 4) {
        a0 += ifeat[(size_t)(i + 0) * D + t];
        a1 += ifeat[(size_t)(i + 1) * D + t];
        a2 += ifeat[(size_t)(i + 2) * D + t];
        a3 += ifeat[(size_t)(i + 3) * D + t];
    }
    for (; i < e; ++i) a0 += ifeat[(size_t)i * D + t];
    float sum = (a0 + a1) + (a2 + a3);
    int cnt = e - s;
    float inv = 1.0f / (float)(cnt > 0 ? cnt : 1);
    out[(size_t)b * 512 + 256 + t] = sum * inv;
}

// K2: feat_v = anchor @ Wv^T + bv, 16 segments per block
__global__ void k_featv(const float* __restrict__ out, const float* __restrict__ Wv,
                        const float* __restrict__ bv, float* __restrict__ feat_v) {
    __shared__ float anc[16][D];
    int b0 = blockIdx.x * 16;
    int t = threadIdx.x; // 256, thread = output column j
#pragma unroll
    for (int r = 0; r < 16; ++r) anc[r][t] = out[(size_t)(b0 + r) * 512 + 256 + t];
    __syncthreads();
    float acc[16];
#pragma unroll
    for (int s = 0; s < 16; ++s) acc[s] = 0.f;
    const float* wrow = Wv + (size_t)t * D;
    for (int k = 0; k < D; k += 4) {
        float4 w = *(const float4*)(wrow + k);
#pragma unroll
        for (int s = 0; s < 16; ++s) {
            acc[s] += anc[s][k] * w.x + anc[s][k + 1] * w.y
                    + anc[s][k + 2] * w.z + anc[s][k + 3] * w.w;
        }
    }
    float bj = bv[t];
#pragma unroll
    for (int s = 0; s < 16; ++s) feat_v[(size_t)(b0 + s) * D + t] = acc[s] + bj;
}

// K3 (MFMA, j-split): e_half[h][n] = sum_{j in half h} we_j * sigmoid(u[n][j])
// Grid 512 x 256 thr (4 waves). Block h=bid&1 stages HALF of Wu (128 j-rows,
// 64 KB bf16 LDS, swizzled) ONCE -> 2 blocks/CU. Main loop barrier-free,
// chunk-outer: af transient (2-deep named pipeline), acc[8] f32x4 -> AGPRs.
// Arch-VGPR demand ~50: safe under any allocator cap (rounds 3-6 lesson:
// the 128KB/512-thr monolith always spilled at a pinned 128-reg cap).
__global__ __launch_bounds__(256, 2)
void k_attn_e_mfma(const float* __restrict__ ifeat, const float* __restrict__ Wu,
                   const float* __restrict__ feat_v, const float* __restrict__ we,
                   const int* __restrict__ seg_ids, float* __restrict__ e_half) {
    __shared__ __bf16 Bs[128 * 256];   // 64 KB; row jl stride 512 B; byte ^= (jl&7)<<4

    int tx = threadIdx.x;
    int lane = tx & 63;
    int w = tx >> 6;
    int ln15 = lane & 15;
    int lg = lane >> 4;
    int h  = blockIdx.x & 1;           // j-half
    int bh = blockIdx.x >> 1;          // 0..255

    // ---- stage Wu[h*128 .. h*128+128) once: thread -> (row jl=tx>>1, k-half kh=tx&1) ----
    {
        int jl = tx >> 1, kh = tx & 1;
        const float* wp = Wu + (size_t)(h * 128 + jl) * D + kh * 128;
        char* rowp = (char*)Bs + jl * 512;
        int sw = (jl & 7) << 4;
#pragma unroll
        for (int q = 0; q < 16; ++q) {
            float4 b0 = *(const float4*)(wp + q * 8);
            float4 b1 = *(const float4*)(wp + q * 8 + 4);
            bf16x8 v;
            v[0] = (__bf16)b0.x; v[1] = (__bf16)b0.y; v[2] = (__bf16)b0.z; v[3] = (__bf16)b0.w;
            v[4] = (__bf16)b1.x; v[5] = (__bf16)b1.y; v[6] = (__bf16)b1.z; v[7] = (__bf16)b1.w;
            *(bf16x8*)(rowp + ((kh * 256 + q * 16) ^ sw)) = v;
        }
    }
    __syncthreads();

    float* eh = e_half + (size_t)h * NN;
    int swr = (ln15 & 7) << 4;               // read swizzle (LDS row = ct*16+ln15, row&7==ln15&7)
    int klo = lg * 16;                       // k-byte offset of this lane-group's 8 elems
    const char* bbase = (const char*)Bs + ln15 * 512;
    const float* feph = feat_v + h * 128 + ln15;
    const float* weh  = we + h * 128 + ln15;

    int wgid = bh * 4 + w;                   // 0..1023 (waves per half)

    for (int item = wgid; item < NN / 16; item += 1024) {
        int nb = item * 16;
        const float* ap = ifeat + (size_t)(nb + ln15) * D + lg * 8;

        f32x4 a0 = (f32x4){0.f,0.f,0.f,0.f}, a1 = a0, a2 = a0, a3 = a0,
              a4 = a0, a5 = a0, a6 = a0, a7 = a0;

        float4 x0, y0, x1, y1;   // 2-deep named A pipeline — all-static
#define LDA0(CH) { x0 = *(const float4*)(ap + (CH) * 32); y0 = *(const float4*)(ap + (CH) * 32 + 4); }
#define LDA1(CH) { x1 = *(const float4*)(ap + (CH) * 32); y1 = *(const float4*)(ap + (CH) * 32 + 4); }
#define CHUNK(CH, XA, YA) { \
    bf16x8 af; \
    af[0] = (__bf16)XA.x; af[1] = (__bf16)XA.y; af[2] = (__bf16)XA.z; af[3] = (__bf16)XA.w; \
    af[4] = (__bf16)YA.x; af[5] = (__bf16)YA.y; af[6] = (__bf16)YA.z; af[7] = (__bf16)YA.w; \
    int kb = ((CH) * 64 + klo) ^ swr; \
    a0 = __builtin_amdgcn_mfma_f32_16x16x32_bf16(af, *(const bf16x8*)(bbase + 0 * 8192 + kb), a0, 0, 0, 0); \
    a1 = __builtin_amdgcn_mfma_f32_16x16x32_bf16(af, *(const bf16x8*)(bbase + 1 * 8192 + kb), a1, 0, 0, 0); \
    a2 = __builtin_amdgcn_mfma_f32_16x16x32_bf16(af, *(const bf16x8*)(bbase + 2 * 8192 + kb), a2, 0, 0, 0); \
    a3 = __builtin_amdgcn_mfma_f32_16x16x32_bf16(af, *(const bf16x8*)(bbase + 3 * 8192 + kb), a3, 0, 0, 0); \
    a4 = __builtin_amdgcn_mfma_f32_16x16x32_bf16(af, *(const bf16x8*)(bbase + 4 * 8192 + kb), a4, 0, 0, 0); \
    a5 = __builtin_amdgcn_mfma_f32_16x16x32_bf16(af, *(const bf16x8*)(bbase + 5 * 8192 + kb), a5, 0, 0, 0); \
    a6 = __builtin_amdgcn_mfma_f32_16x16x32_bf16(af, *(const bf16x8*)(bbase + 6 * 8192 + kb), a6, 0, 0, 0); \
    a7 = __builtin_amdgcn_mfma_f32_16x16x32_bf16(af, *(const bf16x8*)(bbase + 7 * 8192 + kb), a7, 0, 0, 0); }

        LDA0(0);
        LDA1(1); CHUNK(0, x0, y0)
        LDA0(2); CHUNK(1, x1, y1)
        LDA1(3); CHUNK(2, x0, y0)
        LDA0(4); CHUNK(3, x1, y1)
        LDA1(5); CHUNK(4, x0, y0)
        LDA0(6); CHUNK(5, x1, y1)
        LDA1(7); CHUNK(6, x0, y0)
                 CHUNK(7, x1, y1)
#undef LDA0
#undef LDA1
#undef CHUNK

        // ---- epilogue: u = acc + feat_v[seg[row]][col]; part += we*sigmoid(u) ----
        int r0 = nb + lg * 4;
        const float* fp0 = feph + (size_t)seg_ids[r0 + 0] * D;
        const float* fp1 = feph + (size_t)seg_ids[r0 + 1] * D;
        const float* fp2 = feph + (size_t)seg_ids[r0 + 2] * D;
        const float* fp3 = feph + (size_t)seg_ids[r0 + 3] * D;
        float part0 = 0.f, part1 = 0.f, part2 = 0.f, part3 = 0.f;

#define EPI(AC, CT) { \
    float w_ = weh[(CT) * 16]; \
    part0 += w_ / (1.f + __expf(-(AC[0] + fp0[(CT) * 16]))); \
    part1 += w_ / (1.f + __expf(-(AC[1] + fp1[(CT) * 16]))); \
    part2 += w_ / (1.f + __expf(-(AC[2] + fp2[(CT) * 16]))); \
    part3 += w_ / (1.f + __expf(-(AC[3] + fp3[(CT) * 16]))); }

        EPI(a0, 0) EPI(a1, 1) EPI(a2, 2) EPI(a3, 3)
        EPI(a4, 4) EPI(a5, 5) EPI(a6, 6) EPI(a7, 7)
#undef EPI

        // reduce over the 16 col-lanes
#pragma unroll
        for (int off = 8; off >= 1; off >>= 1) {
            part0 += __shfl_xor(part0, off, 64);
            part1 += __shfl_xor(part1, off, 64);
            part2 += __shfl_xor(part2, off, 64);
            part3 += __shfl_xor(part3, off, 64);
        }
        if (ln15 == 0) {
            float4 o = make_float4(part0, part1, part2, part3);
            *(float4*)&eh[r0] = o;
        }
    }
}

// K4: segment softmax (max, denom) + alpha-weighted segment sum -> out[:, 0:256]
// e[i] = e0[i] + e1[i] (j-split halves)
__global__ void k_softmax_rst(const float* __restrict__ ifeat, const int* __restrict__ seg_start,
                              const float* __restrict__ e0, const float* __restrict__ e1,
                              float* __restrict__ out) {
    int b = blockIdx.x;
    int t = threadIdx.x; // 256
    int s = seg_start[b], en = seg_start[b + 1];
    float m = -1e30f;
    for (int i = s + t; i < en; i += 256) m = fmaxf(m, e0[i] + e1[i]);
#pragma unroll
    for (int off = 32; off >= 1; off >>= 1) m = fmaxf(m, __shfl_xor(m, off, 64));
    __shared__ float red[4];
    if ((t & 63) == 0) red[t >> 6] = m;
    __syncthreads();
    float mall = fmaxf(fmaxf(red[0], red[1]), fmaxf(red[2], red[3]));
    float dsum = 0.f;
    for (int i = s + t; i < en; i += 256) dsum += __expf(e0[i] + e1[i] - mall);
#pragma unroll
    for (int off = 32; off >= 1; off >>= 1) dsum += __shfl_xor(dsum, off, 64);
    __shared__ float red2[4];
    if ((t & 63) == 0) red2[t >> 6] = dsum;
    __syncthreads();
    float denom = red2[0] + red2[1] + red2[2] + red2[3];
    float invd = (en > s) ? 1.0f / denom : 0.f;
    float acc = 0.f;
    for (int i = s; i < en; ++i) {
        float alpha = __expf(e0[i] + e1[i] - mall) * invd;
        acc += ifeat[(size_t)i * D + t] * alpha;
    }
    out[(size_t)b * 512 + t] = acc;
}

extern "C" void kernel_launch(void* const* d_in, const int* in_sizes, int n_in,
                              void* d_out, int out_size, void* d_ws, size_t ws_size,
                              hipStream_t stream) {
    const float* ifeat = (const float*)d_in[0];
    const float* Wu    = (const float*)d_in[1];
    const float* Wv    = (const float*)d_in[2];
    const float* bv    = (const float*)d_in[3];
    const float* we    = (const float*)d_in[4];
    const int*   seg   = (const int*)d_in[5];
    float* out = (float*)d_out;

    char* ws = (char*)d_ws;
    int*   seg_start = (int*)ws;                                   // (B+1) ints
    float* feat_v    = (float*)(ws + 16384);                       // B*D floats (2 MB)
    float* e_half    = (float*)(ws + 16384 + (size_t)B * D * 4);   // 2*NN floats (800 KB)

    k_bounds<<<(B + 1 + 255) / 256, 256, 0, stream>>>(seg, seg_start);
    k_anchor<<<B, 256, 0, stream>>>(ifeat, seg_start, out);
    k_featv<<<B / 16, 256, 0, stream>>>(out, Wv, bv, feat_v);
    k_attn_e_mfma<<<512, 256, 0, stream>>>(ifeat, Wu, feat_v, we, seg, e_half);
    k_softmax_rst<<<B, 256, 0, stream>>>(ifeat, seg_start, e_half, e_half + NN, out);
}

// Round 8
// 133.542 us; speedup vs baseline: 3.0624x; 1.4992x over previous
//
#include <hip/hip_runtime.h>
#include <math.h>

#define NN 102400
#define D 256
#define B 2048

typedef __bf16 bf16x8 __attribute__((ext_vector_type(8)));
typedef float f32x4 __attribute__((ext_vector_type(4)));

// K0: seg_start[b] = lower_bound(seg_ids, b); seg_start[B] = NN
__global__ void k_bounds(const int* __restrict__ seg, int* __restrict__ seg_start) {
    int b = blockIdx.x * blockDim.x + threadIdx.x;
    if (b > B) return;
    int lo = 0, hi = NN;
    while (lo < hi) { int mid = (lo + hi) >> 1; if (seg[mid] < b) lo = mid + 1; else hi = mid; }
    seg_start[b] = lo;
}

// K1: anchor (segment mean) -> out[:, 256:512]
__global__ void k_anchor(const float* __restrict__ ifeat, const int* __restrict__ seg_start,
                         float* __restrict__ out) {
    int b = blockIdx.x;
    int t = threadIdx.x; // 256 threads, thread = column
    int s = seg_start[b], e = seg_start[b + 1];
    float a0 = 0.f, a1 = 0.f, a2 = 0.f, a3 = 0.f;
    int i = s;
    for (; i + 4 <= e; i += 4) {
        a0 += ifeat[(size_t)(i + 0) * D + t];
        a1 += ifeat[(size_t)(i + 1) * D + t];
        a2 += ifeat[(size_t)(i + 2) * D + t];
        a3 += ifeat[(size_t)(i + 3) * D + t];
    }
    for (; i < e; ++i) a0 += ifeat[(size_t)i * D + t];
    float sum = (a0 + a1) + (a2 + a3);
    int cnt = e - s;
    float inv = 1.0f / (float)(cnt > 0 ? cnt : 1);
    out[(size_t)b * 512 + 256 + t] = sum * inv;
}

// K2: feat_v = anchor @ Wv^T + bv, 16 segments per block
__global__ void k_featv(const float* __restrict__ out, const float* __restrict__ Wv,
                        const float* __restrict__ bv, float* __restrict__ feat_v) {
    __shared__ float anc[16][D];
    int b0 = blockIdx.x * 16;
    int t = threadIdx.x; // 256, thread = output column j
#pragma unroll
    for (int r = 0; r < 16; ++r) anc[r][t] = out[(size_t)(b0 + r) * 512 + 256 + t];
    __syncthreads();
    float acc[16];
#pragma unroll
    for (int s = 0; s < 16; ++s) acc[s] = 0.f;
    const float* wrow = Wv + (size_t)t * D;
    for (int k = 0; k < D; k += 4) {
        float4 w = *(const float4*)(wrow + k);
#pragma unroll
        for (int s = 0; s < 16; ++s) {
            acc[s] += anc[s][k] * w.x + anc[s][k + 1] * w.y
                    + anc[s][k + 2] * w.z + anc[s][k + 3] * w.w;
        }
    }
    float bj = bv[t];
#pragma unroll
    for (int s = 0; s < 16; ++s) feat_v[(size_t)(b0 + s) * D + t] = acc[s] + bj;
}

// K3 (MFMA, j-split): e_half[h][n] = sum_{j in half h} we_j * sigmoid(u[n][j])
// Grid 512 x 256 thr. Block h=bid&1 stages HALF of Wu (128 rows, 64 KB, swizzled)
// once -> 2 blocks/CU. R8 change vs R7: the 8-chunk body is a ROLLED
// `#pragma unroll 1` loop (1-deep named prefetch). R3-R7 lesson: straight-line
// unrolled bodies let the scheduler hoist all loads -> live-range explosion ->
// scratch spill (WRITE_SIZE 42-338 MB). Rolled loop bounds the scheduling scope.
__global__ __launch_bounds__(256, 2)
void k_attn_e_mfma(const float* __restrict__ ifeat, const float* __restrict__ Wu,
                   const float* __restrict__ feat_v, const float* __restrict__ we,
                   const int* __restrict__ seg_ids, float* __restrict__ e_half) {
    __shared__ __bf16 Bs[128 * 256];   // 64 KB; row jl stride 512 B; byte ^= (jl&7)<<4

    int tx = threadIdx.x;
    int lane = tx & 63;
    int w = tx >> 6;
    int ln15 = lane & 15;
    int lg = lane >> 4;
    int h  = blockIdx.x & 1;           // j-half
    int bh = blockIdx.x >> 1;          // 0..255

    // ---- stage Wu[h*128 .. h*128+128) once: thread -> (row jl=tx>>1, k-half kh=tx&1) ----
    {
        int jl = tx >> 1, kh = tx & 1;
        const float* wp = Wu + (size_t)(h * 128 + jl) * D + kh * 128;
        char* rowp = (char*)Bs + jl * 512;
        int sw = (jl & 7) << 4;
#pragma unroll
        for (int q = 0; q < 16; ++q) {
            float4 b0 = *(const float4*)(wp + q * 8);
            float4 b1 = *(const float4*)(wp + q * 8 + 4);
            bf16x8 v;
            v[0] = (__bf16)b0.x; v[1] = (__bf16)b0.y; v[2] = (__bf16)b0.z; v[3] = (__bf16)b0.w;
            v[4] = (__bf16)b1.x; v[5] = (__bf16)b1.y; v[6] = (__bf16)b1.z; v[7] = (__bf16)b1.w;
            *(bf16x8*)(rowp + ((kh * 256 + q * 16) ^ sw)) = v;
        }
    }
    __syncthreads();

    float* eh = e_half + (size_t)h * NN;
    int swr = (ln15 & 7) << 4;               // read swizzle (LDS row = ct*16+ln15, row&7==ln15&7)
    int klo = lg * 16;                       // k-byte offset of this lane-group's 8 elems
    const char* bbase = (const char*)Bs + ln15 * 512;
    const float* feph = feat_v + h * 128 + ln15;
    const float* weh  = we + h * 128 + ln15;

    int wgid = bh * 4 + w;                   // 0..1023 (waves per half)

    for (int item = wgid; item < NN / 16; item += 1024) {
        int nb = item * 16;
        const float* ap = ifeat + (size_t)(nb + ln15) * D + lg * 8;

        f32x4 a0 = (f32x4){0.f,0.f,0.f,0.f}, a1 = a0, a2 = a0, a3 = a0,
              a4 = a0, a5 = a0, a6 = a0, a7 = a0;

        // rolled chunk loop, 1-deep named-register prefetch (all-static names)
        float4 xc = *(const float4*)(ap);
        float4 yc = *(const float4*)(ap + 4);
#pragma unroll 1
        for (int ch = 0; ch < 8; ++ch) {
            int nx = ((ch + 1) & 7) * 32;              // wrap: last iter re-reads ch0 (in-bounds)
            float4 xn = *(const float4*)(ap + nx);
            float4 yn = *(const float4*)(ap + nx + 4);
            bf16x8 af;
            af[0] = (__bf16)xc.x; af[1] = (__bf16)xc.y; af[2] = (__bf16)xc.z; af[3] = (__bf16)xc.w;
            af[4] = (__bf16)yc.x; af[5] = (__bf16)yc.y; af[6] = (__bf16)yc.z; af[7] = (__bf16)yc.w;
            int kb = (ch * 64 + klo) ^ swr;
            a0 = __builtin_amdgcn_mfma_f32_16x16x32_bf16(af, *(const bf16x8*)(bbase + 0 * 8192 + kb), a0, 0, 0, 0);
            a1 = __builtin_amdgcn_mfma_f32_16x16x32_bf16(af, *(const bf16x8*)(bbase + 1 * 8192 + kb), a1, 0, 0, 0);
            a2 = __builtin_amdgcn_mfma_f32_16x16x32_bf16(af, *(const bf16x8*)(bbase + 2 * 8192 + kb), a2, 0, 0, 0);
            a3 = __builtin_amdgcn_mfma_f32_16x16x32_bf16(af, *(const bf16x8*)(bbase + 3 * 8192 + kb), a3, 0, 0, 0);
            a4 = __builtin_amdgcn_mfma_f32_16x16x32_bf16(af, *(const bf16x8*)(bbase + 4 * 8192 + kb), a4, 0, 0, 0);
            a5 = __builtin_amdgcn_mfma_f32_16x16x32_bf16(af, *(const bf16x8*)(bbase + 5 * 8192 + kb), a5, 0, 0, 0);
            a6 = __builtin_amdgcn_mfma_f32_16x16x32_bf16(af, *(const bf16x8*)(bbase + 6 * 8192 + kb), a6, 0, 0, 0);
            a7 = __builtin_amdgcn_mfma_f32_16x16x32_bf16(af, *(const bf16x8*)(bbase + 7 * 8192 + kb), a7, 0, 0, 0);
            xc = xn; yc = yn;
        }

        // ---- epilogue: u = acc + feat_v[seg[row]][col]; part += we*sigmoid(u) ----
        int r0 = nb + lg * 4;
        const float* fp0 = feph + (size_t)seg_ids[r0 + 0] * D;
        const float* fp1 = feph + (size_t)seg_ids[r0 + 1] * D;
        const float* fp2 = feph + (size_t)seg_ids[r0 + 2] * D;
        const float* fp3 = feph + (size_t)seg_ids[r0 + 3] * D;
        float part0 = 0.f, part1 = 0.f, part2 = 0.f, part3 = 0.f;

#define EPI(AC, CT) { \
    float w_ = weh[(CT) * 16]; \
    part0 += w_ / (1.f + __expf(-(AC[0] + fp0[(CT) * 16]))); \
    part1 += w_ / (1.f + __expf(-(AC[1] + fp1[(CT) * 16]))); \
    part2 += w_ / (1.f + __expf(-(AC[2] + fp2[(CT) * 16]))); \
    part3 += w_ / (1.f + __expf(-(AC[3] + fp3[(CT) * 16]))); }

        EPI(a0, 0) EPI(a1, 1) EPI(a2, 2) EPI(a3, 3)
        EPI(a4, 4) EPI(a5, 5) EPI(a6, 6) EPI(a7, 7)
#undef EPI

        // reduce over the 16 col-lanes
#pragma unroll
        for (int off = 8; off >= 1; off >>= 1) {
            part0 += __shfl_xor(part0, off, 64);
            part1 += __shfl_xor(part1, off, 64);
            part2 += __shfl_xor(part2, off, 64);
            part3 += __shfl_xor(part3, off, 64);
        }
        if (ln15 == 0) {
            float4 o = make_float4(part0, part1, part2, part3);
            *(float4*)&eh[r0] = o;
        }
    }
}

// K4: segment softmax (max, denom) + alpha-weighted segment sum -> out[:, 0:256]
// e[i] = e0[i] + e1[i] (j-split halves)
__global__ void k_softmax_rst(const float* __restrict__ ifeat, const int* __restrict__ seg_start,
                              const float* __restrict__ e0, const float* __restrict__ e1,
                              float* __restrict__ out) {
    int b = blockIdx.x;
    int t = threadIdx.x; // 256
    int s = seg_start[b], en = seg_start[b + 1];
    float m = -1e30f;
    for (int i = s + t; i < en; i += 256) m = fmaxf(m, e0[i] + e1[i]);
#pragma unroll
    for (int off = 32; off >= 1; off >>= 1) m = fmaxf(m, __shfl_xor(m, off, 64));
    __shared__ float red[4];
    if ((t & 63) == 0) red[t >> 6] = m;
    __syncthreads();
    float mall = fmaxf(fmaxf(red[0], red[1]), fmaxf(red[2], red[3]));
    float dsum = 0.f;
    for (int i = s + t; i < en; i += 256) dsum += __expf(e0[i] + e1[i] - mall);
#pragma unroll
    for (int off = 32; off >= 1; off >>= 1) dsum += __shfl_xor(dsum, off, 64);
    __shared__ float red2[4];
    if ((t & 63) == 0) red2[t >> 6] = dsum;
    __syncthreads();
    float denom = red2[0] + red2[1] + red2[2] + red2[3];
    float invd = (en > s) ? 1.0f / denom : 0.f;
    float acc = 0.f;
    for (int i = s; i < en; ++i) {
        float alpha = __expf(e0[i] + e1[i] - mall) * invd;
        acc += ifeat[(size_t)i * D + t] * alpha;
    }
    out[(size_t)b * 512 + t] = acc;
}

extern "C" void kernel_launch(void* const* d_in, const int* in_sizes, int n_in,
                              void* d_out, int out_size, void* d_ws, size_t ws_size,
                              hipStream_t stream) {
    const float* ifeat = (const float*)d_in[0];
    const float* Wu    = (const float*)d_in[1];
    const float* Wv    = (const float*)d_in[2];
    const float* bv    = (const float*)d_in[3];
    const float* we    = (const float*)d_in[4];
    const int*   seg   = (const int*)d_in[5];
    float* out = (float*)d_out;

    char* ws = (char*)d_ws;
    int*   seg_start = (int*)ws;                                   // (B+1) ints
    float* feat_v    = (float*)(ws + 16384);                       // B*D floats (2 MB)
    float* e_half    = (float*)(ws + 16384 + (size_t)B * D * 4);   // 2*NN floats (800 KB)

    k_bounds<<<(B + 1 + 255) / 256, 256, 0, stream>>>(seg, seg_start);
    k_anchor<<<B, 256, 0, stream>>>(ifeat, seg_start, out);
    k_featv<<<B / 16, 256, 0, stream>>>(out, Wv, bv, feat_v);
    k_attn_e_mfma<<<512, 256, 0, stream>>>(ifeat, Wu, feat_v, we, seg, e_half);
    k_softmax_rst<<<B, 256, 0, stream>>>(ifeat, seg_start, e_half, e_half + NN, out);
}

// Round 9
// 127.612 us; speedup vs baseline: 3.2047x; 1.0465x over previous
//
#include <hip/hip_runtime.h>
#include <math.h>

#define NN 102400
#define D 256
#define B 2048

typedef __bf16 bf16x8 __attribute__((ext_vector_type(8)));
typedef float f32x4 __attribute__((ext_vector_type(4)));

// K0: seg_start[b] = lower_bound(seg_ids, b); seg_start[B] = NN
__global__ void k_bounds(const int* __restrict__ seg, int* __restrict__ seg_start) {
    int b = blockIdx.x * blockDim.x + threadIdx.x;
    if (b > B) return;
    int lo = 0, hi = NN;
    while (lo < hi) { int mid = (lo + hi) >> 1; if (seg[mid] < b) lo = mid + 1; else hi = mid; }
    seg_start[b] = lo;
}

// K1: anchor (segment mean) -> out[:, 256:512]
__global__ void k_anchor(const float* __restrict__ ifeat, const int* __restrict__ seg_start,
                         float* __restrict__ out) {
    int b = blockIdx.x;
    int t = threadIdx.x; // 256 threads, thread = column
    int s = seg_start[b], e = seg_start[b + 1];
    float a0 = 0.f, a1 = 0.f, a2 = 0.f, a3 = 0.f;
    int i = s;
    for (; i + 4 <= e; i += 4) {
        a0 += ifeat[(size_t)(i + 0) * D + t];
        a1 += ifeat[(size_t)(i + 1) * D + t];
        a2 += ifeat[(size_t)(i + 2) * D + t];
        a3 += ifeat[(size_t)(i + 3) * D + t];
    }
    for (; i < e; ++i) a0 += ifeat[(size_t)i * D + t];
    float sum = (a0 + a1) + (a2 + a3);
    int cnt = e - s;
    float inv = 1.0f / (float)(cnt > 0 ? cnt : 1);
    out[(size_t)b * 512 + 256 + t] = sum * inv;
}

// K2: feat_v = anchor @ Wv^T + bv, 16 segments per block
__global__ void k_featv(const float* __restrict__ out, const float* __restrict__ Wv,
                        const float* __restrict__ bv, float* __restrict__ feat_v) {
    __shared__ float anc[16][D];
    int b0 = blockIdx.x * 16;
    int t = threadIdx.x; // 256, thread = output column j
#pragma unroll
    for (int r = 0; r < 16; ++r) anc[r][t] = out[(size_t)(b0 + r) * 512 + 256 + t];
    __syncthreads();
    float acc[16];
#pragma unroll
    for (int s = 0; s < 16; ++s) acc[s] = 0.f;
    const float* wrow = Wv + (size_t)t * D;
    for (int k = 0; k < D; k += 4) {
        float4 w = *(const float4*)(wrow + k);
#pragma unroll
        for (int s = 0; s < 16; ++s) {
            acc[s] += anc[s][k] * w.x + anc[s][k + 1] * w.y
                    + anc[s][k + 2] * w.z + anc[s][k + 3] * w.w;
        }
    }
    float bj = bv[t];
#pragma unroll
    for (int s = 0; s < 16; ++s) feat_v[(size_t)(b0 + s) * D + t] = acc[s] + bj;
}

// K3 (MFMA, j-split): e_half[h][n] = sum_{j in half h} we_j * sigmoid(u[n][j])
// Grid 256 x 512 thr (8 waves). Block h=bid&1 stages HALF of Wu (128 rows, 64 KB,
// swizzled) once -> 2 blocks/CU -> 16 waves/CU (R9: was 8; more TLP to hide
// global+LDS latency). Main loop: ROLLED `#pragma unroll 1` chunk loop with 1-deep
// named prefetch (R8 lesson: straight-line bodies -> load hoisting -> spill).
__global__ __launch_bounds__(512, 2)
void k_attn_e_mfma(const float* __restrict__ ifeat, const float* __restrict__ Wu,
                   const float* __restrict__ feat_v, const float* __restrict__ we,
                   const int* __restrict__ seg_ids, float* __restrict__ e_half) {
    __shared__ __bf16 Bs[128 * 256];   // 64 KB; row jl stride 512 B; byte ^= (jl&7)<<4

    int tx = threadIdx.x;
    int lane = tx & 63;
    int w = tx >> 6;                   // 0..7
    int ln15 = lane & 15;
    int lg = lane >> 4;
    int h  = blockIdx.x & 1;           // j-half
    int bh = blockIdx.x >> 1;          // 0..127

    // ---- stage Wu[h*128 ..): thread -> (row jl=tx>>2, k-quarter kh=tx&3), 64 elems ----
    {
        int jl = tx >> 2, kh = tx & 3;
        const float* wp = Wu + (size_t)(h * 128 + jl) * D + kh * 64;
        char* rowp = (char*)Bs + jl * 512;
        int sw = (jl & 7) << 4;
#pragma unroll
        for (int q = 0; q < 8; ++q) {
            float4 b0 = *(const float4*)(wp + q * 8);
            float4 b1 = *(const float4*)(wp + q * 8 + 4);
            bf16x8 v;
            v[0] = (__bf16)b0.x; v[1] = (__bf16)b0.y; v[2] = (__bf16)b0.z; v[3] = (__bf16)b0.w;
            v[4] = (__bf16)b1.x; v[5] = (__bf16)b1.y; v[6] = (__bf16)b1.z; v[7] = (__bf16)b1.w;
            *(bf16x8*)(rowp + ((kh * 128 + q * 16) ^ sw)) = v;
        }
    }
    __syncthreads();

    float* eh = e_half + (size_t)h * NN;
    int swr = (ln15 & 7) << 4;               // read swizzle (LDS row = ct*16+ln15, row&7==ln15&7)
    int klo = lg * 16;                       // k-byte offset of this lane-group's 8 elems
    const char* bbase = (const char*)Bs + ln15 * 512;
    const float* feph = feat_v + h * 128 + ln15;
    const float* weh  = we + h * 128 + ln15;

    int wgid = bh * 8 + w;                   // 0..1023 (waves per half)

    for (int item = wgid; item < NN / 16; item += 1024) {
        int nb = item * 16;
        const float* ap = ifeat + (size_t)(nb + ln15) * D + lg * 8;

        f32x4 a0 = (f32x4){0.f,0.f,0.f,0.f}, a1 = a0, a2 = a0, a3 = a0,
              a4 = a0, a5 = a0, a6 = a0, a7 = a0;

        // rolled chunk loop, 1-deep named-register prefetch (all-static names)
        float4 xc = *(const float4*)(ap);
        float4 yc = *(const float4*)(ap + 4);
#pragma unroll 1
        for (int ch = 0; ch < 8; ++ch) {
            int nx = ((ch + 1) & 7) * 32;              // wrap: last iter re-reads ch0 (in-bounds)
            float4 xn = *(const float4*)(ap + nx);
            float4 yn = *(const float4*)(ap + nx + 4);
            bf16x8 af;
            af[0] = (__bf16)xc.x; af[1] = (__bf16)xc.y; af[2] = (__bf16)xc.z; af[3] = (__bf16)xc.w;
            af[4] = (__bf16)yc.x; af[5] = (__bf16)yc.y; af[6] = (__bf16)yc.z; af[7] = (__bf16)yc.w;
            int kb = (ch * 64 + klo) ^ swr;
            a0 = __builtin_amdgcn_mfma_f32_16x16x32_bf16(af, *(const bf16x8*)(bbase + 0 * 8192 + kb), a0, 0, 0, 0);
            a1 = __builtin_amdgcn_mfma_f32_16x16x32_bf16(af, *(const bf16x8*)(bbase + 1 * 8192 + kb), a1, 0, 0, 0);
            a2 = __builtin_amdgcn_mfma_f32_16x16x32_bf16(af, *(const bf16x8*)(bbase + 2 * 8192 + kb), a2, 0, 0, 0);
            a3 = __builtin_amdgcn_mfma_f32_16x16x32_bf16(af, *(const bf16x8*)(bbase + 3 * 8192 + kb), a3, 0, 0, 0);
            a4 = __builtin_amdgcn_mfma_f32_16x16x32_bf16(af, *(const bf16x8*)(bbase + 4 * 8192 + kb), a4, 0, 0, 0);
            a5 = __builtin_amdgcn_mfma_f32_16x16x32_bf16(af, *(const bf16x8*)(bbase + 5 * 8192 + kb), a5, 0, 0, 0);
            a6 = __builtin_amdgcn_mfma_f32_16x16x32_bf16(af, *(const bf16x8*)(bbase + 6 * 8192 + kb), a6, 0, 0, 0);
            a7 = __builtin_amdgcn_mfma_f32_16x16x32_bf16(af, *(const bf16x8*)(bbase + 7 * 8192 + kb), a7, 0, 0, 0);
            xc = xn; yc = yn;
        }

        // ---- epilogue: u = acc + feat_v[seg[row]][col]; part += we*sigmoid(u) ----
        int r0 = nb + lg * 4;
        const float* fp0 = feph + (size_t)seg_ids[r0 + 0] * D;
        const float* fp1 = feph + (size_t)seg_ids[r0 + 1] * D;
        const float* fp2 = feph + (size_t)seg_ids[r0 + 2] * D;
        const float* fp3 = feph + (size_t)seg_ids[r0 + 3] * D;
        float part0 = 0.f, part1 = 0.f, part2 = 0.f, part3 = 0.f;

#define EPI(AC, CT) { \
    float w_ = weh[(CT) * 16]; \
    part0 += w_ / (1.f + __expf(-(AC[0] + fp0[(CT) * 16]))); \
    part1 += w_ / (1.f + __expf(-(AC[1] + fp1[(CT) * 16]))); \
    part2 += w_ / (1.f + __expf(-(AC[2] + fp2[(CT) * 16]))); \
    part3 += w_ / (1.f + __expf(-(AC[3] + fp3[(CT) * 16]))); }

        EPI(a0, 0) EPI(a1, 1) EPI(a2, 2) EPI(a3, 3)
        EPI(a4, 4) EPI(a5, 5) EPI(a6, 6) EPI(a7, 7)
#undef EPI

        // reduce over the 16 col-lanes
#pragma unroll
        for (int off = 8; off >= 1; off >>= 1) {
            part0 += __shfl_xor(part0, off, 64);
            part1 += __shfl_xor(part1, off, 64);
            part2 += __shfl_xor(part2, off, 64);
            part3 += __shfl_xor(part3, off, 64);
        }
        if (ln15 == 0) {
            float4 o = make_float4(part0, part1, part2, part3);
            *(float4*)&eh[r0] = o;
        }
    }
}

// K4: segment softmax (max, denom) + alpha-weighted segment sum -> out[:, 0:256]
// e[i] = e0[i] + e1[i] (j-split halves). Phase 3 unrolled x4: 4 row-loads in flight
// (serial-row loop was latency-bound).
__global__ void k_softmax_rst(const float* __restrict__ ifeat, const int* __restrict__ seg_start,
                              const float* __restrict__ e0, const float* __restrict__ e1,
                              float* __restrict__ out) {
    int b = blockIdx.x;
    int t = threadIdx.x; // 256
    int s = seg_start[b], en = seg_start[b + 1];
    float m = -1e30f;
    for (int i = s + t; i < en; i += 256) m = fmaxf(m, e0[i] + e1[i]);
#pragma unroll
    for (int off = 32; off >= 1; off >>= 1) m = fmaxf(m, __shfl_xor(m, off, 64));
    __shared__ float red[4];
    if ((t & 63) == 0) red[t >> 6] = m;
    __syncthreads();
    float mall = fmaxf(fmaxf(red[0], red[1]), fmaxf(red[2], red[3]));
    float dsum = 0.f;
    for (int i = s + t; i < en; i += 256) dsum += __expf(e0[i] + e1[i] - mall);
#pragma unroll
    for (int off = 32; off >= 1; off >>= 1) dsum += __shfl_xor(dsum, off, 64);
    __shared__ float red2[4];
    if ((t & 63) == 0) red2[t >> 6] = dsum;
    __syncthreads();
    float denom = red2[0] + red2[1] + red2[2] + red2[3];
    float invd = (en > s) ? 1.0f / denom : 0.f;
    float ac0 = 0.f, ac1 = 0.f, ac2 = 0.f, ac3 = 0.f;
    int i = s;
    for (; i + 4 <= en; i += 4) {
        float al0 = __expf(e0[i + 0] + e1[i + 0] - mall) * invd;
        float al1 = __expf(e0[i + 1] + e1[i + 1] - mall) * invd;
        float al2 = __expf(e0[i + 2] + e1[i + 2] - mall) * invd;
        float al3 = __expf(e0[i + 3] + e1[i + 3] - mall) * invd;
        ac0 += ifeat[(size_t)(i + 0) * D + t] * al0;
        ac1 += ifeat[(size_t)(i + 1) * D + t] * al1;
        ac2 += ifeat[(size_t)(i + 2) * D + t] * al2;
        ac3 += ifeat[(size_t)(i + 3) * D + t] * al3;
    }
    for (; i < en; ++i) {
        float al = __expf(e0[i] + e1[i] - mall) * invd;
        ac0 += ifeat[(size_t)i * D + t] * al;
    }
    out[(size_t)b * 512 + t] = (ac0 + ac1) + (ac2 + ac3);
}

extern "C" void kernel_launch(void* const* d_in, const int* in_sizes, int n_in,
                              void* d_out, int out_size, void* d_ws, size_t ws_size,
                              hipStream_t stream) {
    const float* ifeat = (const float*)d_in[0];
    const float* Wu    = (const float*)d_in[1];
    const float* Wv    = (const float*)d_in[2];
    const float* bv    = (const float*)d_in[3];
    const float* we    = (const float*)d_in[4];
    const int*   seg   = (const int*)d_in[5];
    float* out = (float*)d_out;

    char* ws = (char*)d_ws;
    int*   seg_start = (int*)ws;                                   // (B+1) ints
    float* feat_v    = (float*)(ws + 16384);                       // B*D floats (2 MB)
    float* e_half    = (float*)(ws + 16384 + (size_t)B * D * 4);   // 2*NN floats (800 KB)

    k_bounds<<<(B + 1 + 255) / 256, 256, 0, stream>>>(seg, seg_start);
    k_anchor<<<B, 256, 0, stream>>>(ifeat, seg_start, out);
    k_featv<<<B / 16, 256, 0, stream>>>(out, Wv, bv, feat_v);
    k_attn_e_mfma<<<256, 512, 0, stream>>>(ifeat, Wu, feat_v, we, seg, e_half);
    k_softmax_rst<<<B, 256, 0, stream>>>(ifeat, seg_start, e_half, e_half + NN, out);
}